// Round 7
// baseline (156.537 us; speedup 1.0000x reference)
//
#include <hip/hip_runtime.h>

// B=8,H=8,S=1024,D=64 fp32 attention, raw-exp softmax, multiplicative key mask.
// Outputs: context[64,1024,64] then scores[64,1024,1024], both fp32.
// R7: phase-split. k1: cvt K/V->f16 (+V transpose). k2: rowsum -> inv (ws).
// k3: recompute QK, scale by inv, store scores in-loop (even store stream),
// accumulate normalized PV, ctx combine. No E staging, minimal barriers.

typedef float    f32x4 __attribute__((ext_vector_type(4)));
typedef _Float16 f16x8 __attribute__((ext_vector_type(8)));
typedef _Float16 f16x4 __attribute__((ext_vector_type(4)));

#define MFMA32(A, B, C) __builtin_amdgcn_mfma_f32_16x16x32_f16((A), (B), (C), 0, 0, 0)
#define MFMA16(A, B, C) __builtin_amdgcn_mfma_f32_16x16x16f16((A), (B), (C), 0, 0, 0)

#define BHN 64
#define SEQ 1024
#define DIM 64

__device__ inline f16x8 cvt8(f32x4 a, f32x4 b) {
    f16x8 r;
    r[0] = (_Float16)a[0]; r[1] = (_Float16)a[1]; r[2] = (_Float16)a[2]; r[3] = (_Float16)a[3];
    r[4] = (_Float16)b[0]; r[5] = (_Float16)b[1]; r[6] = (_Float16)b[2]; r[7] = (_Float16)b[3];
    return r;
}

// ---- k1: K -> f16 same layout; V -> f16 transposed per (b,h): VT[bh][d][key].
__global__ __launch_bounds__(256)
void cvt_kv(const float* __restrict__ K, const float* __restrict__ V,
            _Float16* __restrict__ Kh, _Float16* __restrict__ VT)
{
    __shared__ _Float16 tile[128 * 65];
    const int bh = blockIdx.x >> 3;
    const int kc = blockIdx.x & 7;
    const int t  = threadIdx.x;
    const size_t base = ((size_t)bh * SEQ + (size_t)kc * 128) * DIM;

    for (int it = 0; it < 8; ++it) {
        int idx = it * 256 + t;
        int key = idx >> 4;
        int c4  = idx & 15;
        f32x4 kv = *(const f32x4*)(K + base + key * DIM + c4 * 4);
        f32x4 vv = *(const f32x4*)(V + base + key * DIM + c4 * 4);
        f16x4 kh4;
        kh4[0] = (_Float16)kv[0]; kh4[1] = (_Float16)kv[1];
        kh4[2] = (_Float16)kv[2]; kh4[3] = (_Float16)kv[3];
        *(f16x4*)(Kh + base + key * DIM + c4 * 4) = kh4;
        tile[key * 65 + c4 * 4 + 0] = (_Float16)vv[0];
        tile[key * 65 + c4 * 4 + 1] = (_Float16)vv[1];
        tile[key * 65 + c4 * 4 + 2] = (_Float16)vv[2];
        tile[key * 65 + c4 * 4 + 3] = (_Float16)vv[3];
    }
    __syncthreads();
    for (int it = 0; it < 4; ++it) {
        int idx = it * 256 + t;
        int dd = idx >> 4;
        int kg = idx & 15;
        f16x8 o;
        #pragma unroll
        for (int j = 0; j < 8; ++j) o[j] = tile[(kg * 8 + j) * 65 + dd];
        *(f16x8*)(VT + ((size_t)bh * DIM + dd) * SEQ + (size_t)kc * 128 + kg * 8) = o;
    }
}

// ---- k2: rowsums -> inv. Grid 1024 (= 64 bh x 16 q-blocks of 64 rows), 4 waves.
// Wave w owns key quarter. Swapped QK^T: lane qrow = lane&15, keys (lane>>4)*4+i.
template <bool PRECONV>
__global__ __launch_bounds__(256, 4)
void rowsum_k(const float* __restrict__ Q, const float* __restrict__ K,
              const float* __restrict__ mask, const _Float16* __restrict__ Kh,
              float* __restrict__ invp)
{
    __shared__ float rs[4][4][16];
    const int bid = blockIdx.x;
    const int wg  = ((bid & 7) << 7) | (bid >> 3);   // XCD-bijective (1024 % 8 == 0)
    const int bh  = wg >> 4;
    const int qb  = wg & 15;
    const int b   = bh >> 3;
    const int w    = threadIdx.x >> 6;
    const int lane = threadIdx.x & 63;
    const int col  = lane & 15;
    const int g    = lane >> 4;
    const int q0   = qb * 64;
    const int kb   = w * 256;
    const float scale = 0.125f;

    f16x8 qf[4][2];
    {
        const float* qbase = Q + ((size_t)bh * SEQ + q0) * DIM;
        #pragma unroll
        for (int s = 0; s < 4; ++s)
            #pragma unroll
            for (int f = 0; f < 2; ++f) {
                const float* p = qbase + (s * 16 + col) * DIM + f * 32 + g * 8;
                qf[s][f] = cvt8(*(const f32x4*)p, *(const f32x4*)(p + 4));
            }
    }
    const float* mb = mask + (size_t)b * SEQ + kb;

    float rsum[4] = {0.f, 0.f, 0.f, 0.f};
    for (int kt = 0; kt < 16; ++kt) {
        f16x8 kf0, kf1;
        if (PRECONV) {
            const _Float16* kp = Kh + ((size_t)bh * SEQ + kb + kt * 16 + col) * DIM + g * 8;
            kf0 = *(const f16x8*)kp;
            kf1 = *(const f16x8*)(kp + 32);
        } else {
            const float* kp = K + ((size_t)bh * SEQ + kb + kt * 16 + col) * DIM + g * 8;
            kf0 = cvt8(*(const f32x4*)kp,        *(const f32x4*)(kp + 4));
            kf1 = cvt8(*(const f32x4*)(kp + 32), *(const f32x4*)(kp + 36));
        }
        f32x4 m4 = *(const f32x4*)(mb + kt * 16 + g * 4);
        #pragma unroll
        for (int s = 0; s < 4; ++s) {
            f32x4 acc = {0.f, 0.f, 0.f, 0.f};
            acc = MFMA32(kf0, qf[s][0], acc);
            acc = MFMA32(kf1, qf[s][1], acc);
            rsum[s] += __expf(acc[0] * scale) * m4[0] + __expf(acc[1] * scale) * m4[1]
                     + __expf(acc[2] * scale) * m4[2] + __expf(acc[3] * scale) * m4[3];
        }
    }
    #pragma unroll
    for (int s = 0; s < 4; ++s) {
        float r = rsum[s];
        r += __shfl_xor(r, 16, 64);
        r += __shfl_xor(r, 32, 64);
        rsum[s] = r;
    }
    if (g == 0) {
        #pragma unroll
        for (int s = 0; s < 4; ++s) rs[w][s][col] = rsum[s];
    }
    __syncthreads();
    if (w == 0) {
        const int r = lane;   // 64 rows
        const float t = rs[0][r >> 4][r & 15] + rs[1][r >> 4][r & 15]
                      + rs[2][r >> 4][r & 15] + rs[3][r >> 4][r & 15];
        invp[(size_t)bh * SEQ + q0 + r] = 1.0f / (t + 1e-8f);
    }
}

// ---- k3: scores + PV. Grid 2048 (64 bh x 32 q-blocks of 32 rows), 4 waves =
// key quarters. Stores normalized scores in-loop (even stream), PV normalized.
template <bool PRECONV>
__global__ __launch_bounds__(256, 2)
void scorepv_k(const float* __restrict__ Q, const float* __restrict__ K,
               const float* __restrict__ V, const float* __restrict__ mask,
               const _Float16* __restrict__ Kh, const _Float16* __restrict__ VT,
               const float* __restrict__ invp,
               float* __restrict__ ctx, float* __restrict__ scores)
{
    __shared__ float cbuf[3][32][64];   // 24 KB: cross-wave PV combine

    const int bid = blockIdx.x;
    const int wg  = ((bid & 7) << 8) | (bid >> 3);   // XCD-bijective (2048 % 8 == 0)
    const int bh  = wg >> 5;
    const int qb  = wg & 31;
    const int b   = bh >> 3;
    const int w    = threadIdx.x >> 6;
    const int lane = threadIdx.x & 63;
    const int col  = lane & 15;
    const int g    = lane >> 4;
    const int q0   = qb * 32;
    const int kb   = w * 256;
    const float scale = 0.125f;

    f16x8 qf[2][2];
    {
        const float* qbase = Q + ((size_t)bh * SEQ + q0) * DIM;
        #pragma unroll
        for (int s = 0; s < 2; ++s)
            #pragma unroll
            for (int f = 0; f < 2; ++f) {
                const float* p = qbase + (s * 16 + col) * DIM + f * 32 + g * 8;
                qf[s][f] = cvt8(*(const f32x4*)p, *(const f32x4*)(p + 4));
            }
    }
    const float inv0 = invp[(size_t)bh * SEQ + q0 + col];
    const float inv1 = invp[(size_t)bh * SEQ + q0 + 16 + col];
    const float* mb = mask + (size_t)b * SEQ + kb;
    const _Float16* vtb = VT + (size_t)bh * DIM * SEQ + kb;
    float* srow0 = scores + ((size_t)bh * SEQ + q0) * SEQ + kb;

    f32x4 cacc[2][4];
    #pragma unroll
    for (int s = 0; s < 2; ++s)
        #pragma unroll
        for (int dt = 0; dt < 4; ++dt) cacc[s][dt] = (f32x4){0.f, 0.f, 0.f, 0.f};

    // one-ahead prefetch registers
    f16x8 k0, k1;
    f32x4 m4;
    f16x4 vt[4];
    if (PRECONV) {
        const _Float16* kp = Kh + ((size_t)bh * SEQ + kb + col) * DIM + g * 8;
        k0 = *(const f16x8*)kp;
        k1 = *(const f16x8*)(kp + 32);
        #pragma unroll
        for (int dt = 0; dt < 4; ++dt)
            vt[dt] = *(const f16x4*)(vtb + ((size_t)(dt * 16 + col)) * SEQ + g * 4);
    } else {
        const float* kp = K + ((size_t)bh * SEQ + kb + col) * DIM + g * 8;
        k0 = cvt8(*(const f32x4*)kp,        *(const f32x4*)(kp + 4));
        k1 = cvt8(*(const f32x4*)(kp + 32), *(const f32x4*)(kp + 36));
        #pragma unroll
        for (int dt = 0; dt < 4; ++dt)
            #pragma unroll
            for (int i = 0; i < 4; ++i)
                vt[dt][i] = (_Float16)V[((size_t)bh * SEQ + kb + g * 4 + i) * DIM + dt * 16 + col];
    }
    m4 = *(const f32x4*)(mb + g * 4);

    for (int kt = 0; kt < 16; ++kt) {
        const int ktn = (kt + 1) & 15;
        f16x8 n0, n1;
        f16x4 nvt[4];
        if (PRECONV) {
            const _Float16* kp = Kh + ((size_t)bh * SEQ + kb + ktn * 16 + col) * DIM + g * 8;
            n0 = *(const f16x8*)kp;
            n1 = *(const f16x8*)(kp + 32);
            #pragma unroll
            for (int dt = 0; dt < 4; ++dt)
                nvt[dt] = *(const f16x4*)(vtb + ((size_t)(dt * 16 + col)) * SEQ + ktn * 16 + g * 4);
        } else {
            const float* kp = K + ((size_t)bh * SEQ + kb + ktn * 16 + col) * DIM + g * 8;
            n0 = cvt8(*(const f32x4*)kp,        *(const f32x4*)(kp + 4));
            n1 = cvt8(*(const f32x4*)(kp + 32), *(const f32x4*)(kp + 36));
            #pragma unroll
            for (int dt = 0; dt < 4; ++dt)
                #pragma unroll
                for (int i = 0; i < 4; ++i)
                    nvt[dt][i] = (_Float16)V[((size_t)bh * SEQ + kb + ktn * 16 + g * 4 + i) * DIM + dt * 16 + col];
        }
        f32x4 nm = *(const f32x4*)(mb + ktn * 16 + g * 4);

        f16x4 pf[2];
        #pragma unroll
        for (int s = 0; s < 2; ++s) {
            const float invs = s ? inv1 : inv0;
            f32x4 acc = {0.f, 0.f, 0.f, 0.f};
            acc = MFMA32(k0, qf[s][0], acc);
            acc = MFMA32(k1, qf[s][1], acc);
            f32x4 p;
            p[0] = __expf(acc[0] * scale) * m4[0] * invs;
            p[1] = __expf(acc[1] * scale) * m4[1] * invs;
            p[2] = __expf(acc[2] * scale) * m4[2] * invs;
            p[3] = __expf(acc[3] * scale) * m4[3] * invs;
            *(f32x4*)(srow0 + ((size_t)(s * 16 + col)) * SEQ + kt * 16 + g * 4) = p;
            f16x4 ph;
            ph[0] = (_Float16)p[0]; ph[1] = (_Float16)p[1];
            ph[2] = (_Float16)p[2]; ph[3] = (_Float16)p[3];
            pf[s] = ph;
        }
        #pragma unroll
        for (int dt = 0; dt < 4; ++dt) {
            cacc[0][dt] = MFMA16(vt[dt], pf[0], cacc[0][dt]);
            cacc[1][dt] = MFMA16(vt[dt], pf[1], cacc[1][dt]);
        }
        k0 = n0; k1 = n1; m4 = nm;
        #pragma unroll
        for (int dt = 0; dt < 4; ++dt) vt[dt] = nvt[dt];
    }

    // ---- ctx combine (PV already normalized)
    if (w != 0) {
        #pragma unroll
        for (int s = 0; s < 2; ++s)
            #pragma unroll
            for (int dt = 0; dt < 4; ++dt)
                #pragma unroll
                for (int j = 0; j < 4; ++j)
                    cbuf[w - 1][s * 16 + dt * 4 + j][lane] = cacc[s][dt][j];
    }
    __syncthreads();
    if (w == 0) {
        #pragma unroll
        for (int s = 0; s < 2; ++s)
            #pragma unroll
            for (int dt = 0; dt < 4; ++dt) {
                f32x4 r = cacc[s][dt];
                #pragma unroll
                for (int ww = 0; ww < 3; ++ww)
                    #pragma unroll
                    for (int j = 0; j < 4; ++j)
                        r[j] += cbuf[ww][s * 16 + dt * 4 + j][lane];
                *(f32x4*)(ctx + ((size_t)bh * SEQ + q0 + s * 16 + col) * DIM + dt * 16 + g * 4) = r;
            }
    }
}

extern "C" void kernel_launch(void* const* d_in, const int* in_sizes, int n_in,
                              void* d_out, int out_size, void* d_ws, size_t ws_size,
                              hipStream_t stream)
{
    const float* Q    = (const float*)d_in[0];
    const float* K    = (const float*)d_in[1];
    const float* V    = (const float*)d_in[2];
    const float* mask = (const float*)d_in[3];
    float* ctx    = (float*)d_out;
    float* scores = ctx + (size_t)BHN * SEQ * DIM;

    const size_t elems = (size_t)BHN * SEQ * DIM;           // 4,194,304
    const size_t inv_bytes = (size_t)BHN * SEQ * sizeof(float);   // 256 KB
    const size_t need = elems * 2 * sizeof(_Float16) + inv_bytes; // ~16.25 MB

    if (ws_size >= need) {
        _Float16* Kh   = (_Float16*)d_ws;
        _Float16* VT   = Kh + elems;
        float*    invp = (float*)(VT + elems);
        cvt_kv<<<512, 256, 0, stream>>>(K, V, Kh, VT);
        rowsum_k<true><<<1024, 256, 0, stream>>>(Q, K, mask, Kh, invp);
        scorepv_k<true><<<2048, 256, 0, stream>>>(Q, K, V, mask, Kh, VT, invp, ctx, scores);
    } else {
        float* invp = (float*)d_ws;   // needs only 256 KB
        rowsum_k<false><<<1024, 256, 0, stream>>>(Q, K, mask, nullptr, invp);
        scorepv_k<false><<<2048, 256, 0, stream>>>(Q, K, V, mask, nullptr, nullptr, invp, ctx, scores);
    }
}